// Round 5
// baseline (1456.366 us; speedup 1.0000x reference)
//
#include <hip/hip_runtime.h>
#include <hip/hip_cooperative_groups.h>
#include <math.h>

namespace cg = cooperative_groups;

#define BB 64
#define TT 32
#define II 512
#define HH 256
#define ZN 1024   // 4*H
#define OO 512
#define NPRE 25

typedef unsigned short u16;
typedef short bfrag __attribute__((ext_vector_type(8)));   // 8 bf16 (4 VGPRs)
typedef float f32x4 __attribute__((ext_vector_type(4)));

__device__ __forceinline__ float sigm_(float x) { return 1.f / (1.f + __expf(-x)); }
__device__ __forceinline__ float tanh_(float x) { return 1.f - 2.f / (__expf(2.f * x) + 1.f); }

__device__ __forceinline__ u16 f2bf(float x) {
    union { float f; unsigned u; } v; v.f = x;
    unsigned r = v.u + 0x7fffu + ((v.u >> 16) & 1u);   // RNE
    return (u16)(r >> 16);
}
__device__ __forceinline__ float bf2f(u16 b) {
    union { unsigned u; float f; } v; v.u = ((unsigned)b) << 16; return v.f;
}

// ---------------------------------------------------------------------------
// Fragment prep: src fp32 [D][ld] row-major -> fragment-linear bf16 hi/lo.
//   idx = ((kt*T + t)*64 + l)*8 + i ; d = t*16 + (l&15) ; k = kt*32 + ((l>>4)<<3) + i
// grid: (2*T, KT), 256 threads. T inferred from gridDim.x.
// ---------------------------------------------------------------------------
__global__ __launch_bounds__(256) void prep_frag(
    const float* __restrict__ src, int ld,
    u16* __restrict__ hi, u16* __restrict__ lo)
{
    const int T  = gridDim.x >> 1;
    const int e2 = blockIdx.x * 256 + threadIdx.x;
    const int kt = blockIdx.y;
    const int i = e2 & 7, l = (e2 >> 3) & 63, t = e2 >> 9;
    const int d = t * 16 + (l & 15);
    const int k = kt * 32 + ((l >> 4) << 3) + i;
    const float v = src[(size_t)d * ld + k];
    const u16 h = f2bf(v);
    const size_t o = (size_t)kt * ((size_t)T * 512) + e2;
    hi[o] = h;
    lo[o] = f2bf(v - bf2f(h));
}

// x in t-major A-frag layout: M=2048 with m = t*64 + row. K=512, MT=128, KT=16.
__global__ __launch_bounds__(256) void prep_x_tmajor(
    const float* __restrict__ x, u16* __restrict__ hi, u16* __restrict__ lo)
{
    const int e2 = blockIdx.x * 256 + threadIdx.x;   // 0..65535 within kt slab
    const int kt = blockIdx.y;
    const int i = e2 & 7, l = (e2 >> 3) & 63, mt = e2 >> 9;
    const int d = mt * 16 + (l & 15);                // m = t*64 + row
    const int t = d >> 6, row = d & 63;
    const int k = kt * 32 + ((l >> 4) << 3) + i;
    const float v = x[((size_t)row * TT + t) * II + k];
    const u16 h = f2bf(v);
    const size_t o = (size_t)kt * 65536 + e2;
    hi[o] = h;
    lo[o] = f2bf(v - bf2f(h));
}

// ---------------------------------------------------------------------------
// Register-fragment MFMA GEMM (bf16 x3 ~= fp32), row-major output.
// Used for the final projection. grid: (N/256, M/64)
// ---------------------------------------------------------------------------
__global__ __launch_bounds__(256) void gemm_mfma(
    const u16* __restrict__ Ahi, const u16* __restrict__ Alo, const int MT, const int kt0,
    const u16* __restrict__ Bhi, const u16* __restrict__ Blo, const int NT,
    const float* __restrict__ bias,
    float* __restrict__ C, const int ldc, const int KT)
{
    const int tid = threadIdx.x;
    const int w = tid >> 6, l = tid & 63;
    const int mt0 = blockIdx.y * 4;
    const int nt0 = blockIdx.x * 16 + w * 4;

    f32x4 acc[4][4];
    #pragma unroll
    for (int a = 0; a < 4; ++a)
        #pragma unroll
        for (int b = 0; b < 4; ++b) acc[a][b] = (f32x4){0.f, 0.f, 0.f, 0.f};

    bfrag ah0[4], al0[4], bh0[4], bl0[4];
    bfrag ah1[4], al1[4], bh1[4], bl1[4];

#define LOADF(AH, AL, BH, BL, KIDX) do {                                          \
    const int kk_ = (KIDX);                                                      \
    _Pragma("unroll") for (int mt = 0; mt < 4; ++mt) {                            \
        const size_t oa = (((size_t)(kt0 + kk_) * MT + mt0 + mt) * 64 + l) * 8;   \
        AH[mt] = *(const bfrag*)(Ahi + oa); AL[mt] = *(const bfrag*)(Alo + oa); } \
    _Pragma("unroll") for (int j = 0; j < 4; ++j) {                               \
        const size_t ob = (((size_t)kk_ * NT + nt0 + j) * 64 + l) * 8;            \
        BH[j] = *(const bfrag*)(Bhi + ob); BL[j] = *(const bfrag*)(Blo + ob); }   \
} while (0)

#define MFMAS(AH, AL, BH, BL) do {                                                \
    _Pragma("unroll") for (int mt = 0; mt < 4; ++mt)                              \
    _Pragma("unroll") for (int j = 0; j < 4; ++j) {                               \
        acc[mt][j] = __builtin_amdgcn_mfma_f32_16x16x32_bf16(AH[mt], BH[j], acc[mt][j], 0, 0, 0); \
        acc[mt][j] = __builtin_amdgcn_mfma_f32_16x16x32_bf16(AH[mt], BL[j], acc[mt][j], 0, 0, 0); \
        acc[mt][j] = __builtin_amdgcn_mfma_f32_16x16x32_bf16(AL[mt], BH[j], acc[mt][j], 0, 0, 0); } \
} while (0)

    LOADF(ah0, al0, bh0, bl0, 0);
    for (int kt = 0; kt < KT; kt += 2) {
        LOADF(ah1, al1, bh1, bl1, kt + 1);
        MFMAS(ah0, al0, bh0, bl0);
        if (kt + 2 < KT) LOADF(ah0, al0, bh0, bl0, kt + 2);
        MFMAS(ah1, al1, bh1, bl1);
    }

    const int rsub = (l >> 4) << 2;
    #pragma unroll
    for (int j = 0; j < 4; ++j) {
        const int col = (nt0 + j) * 16 + (l & 15);
        const float bv = bias[col];
        #pragma unroll
        for (int mt = 0; mt < 4; ++mt)
            #pragma unroll
            for (int reg = 0; reg < 4; ++reg)
                C[(size_t)((mt0 + mt) * 16 + rsub + reg) * ldc + col] = acc[mt][j][reg] + bv;
    }
#undef LOADF
#undef MFMAS
}

// ---------------------------------------------------------------------------
// xg-producer GEMM: A = x t-major frags (blockIdx.y = t), B = w_ih frags.
// Output in MFMA C/D fragment-linear layout consumed directly by lstm_runs_k:
//   xgP[(((t*64 + nt)*4 + mt)*64 + l)*4 + reg], nt = z-col tile 0..63
// ---------------------------------------------------------------------------
__global__ __launch_bounds__(256) void gemm_xg(
    const u16* __restrict__ Ahi, const u16* __restrict__ Alo, const int kt0,
    const u16* __restrict__ Bhi, const u16* __restrict__ Blo,
    const float* __restrict__ bias,
    float* __restrict__ out, const int KT)
{
    const int MT = 128, NT = 64;
    const int tid = threadIdx.x;
    const int w = tid >> 6, l = tid & 63;
    const int t = blockIdx.y;
    const int mt0 = t * 4;
    const int nt0 = blockIdx.x * 16 + w * 4;

    f32x4 acc[4][4];
    #pragma unroll
    for (int a = 0; a < 4; ++a)
        #pragma unroll
        for (int b = 0; b < 4; ++b) acc[a][b] = (f32x4){0.f, 0.f, 0.f, 0.f};

    bfrag ah0[4], al0[4], bh0[4], bl0[4];
    bfrag ah1[4], al1[4], bh1[4], bl1[4];

#define LOADF(AH, AL, BH, BL, KIDX) do {                                          \
    const int kk_ = (KIDX);                                                      \
    _Pragma("unroll") for (int mt = 0; mt < 4; ++mt) {                            \
        const size_t oa = (((size_t)(kt0 + kk_) * MT + mt0 + mt) * 64 + l) * 8;   \
        AH[mt] = *(const bfrag*)(Ahi + oa); AL[mt] = *(const bfrag*)(Alo + oa); } \
    _Pragma("unroll") for (int j = 0; j < 4; ++j) {                               \
        const size_t ob = (((size_t)kk_ * NT + nt0 + j) * 64 + l) * 8;            \
        BH[j] = *(const bfrag*)(Bhi + ob); BL[j] = *(const bfrag*)(Blo + ob); }   \
} while (0)

#define MFMAS(AH, AL, BH, BL) do {                                                \
    _Pragma("unroll") for (int mt = 0; mt < 4; ++mt)                              \
    _Pragma("unroll") for (int j = 0; j < 4; ++j) {                               \
        acc[mt][j] = __builtin_amdgcn_mfma_f32_16x16x32_bf16(AH[mt], BH[j], acc[mt][j], 0, 0, 0); \
        acc[mt][j] = __builtin_amdgcn_mfma_f32_16x16x32_bf16(AH[mt], BL[j], acc[mt][j], 0, 0, 0); \
        acc[mt][j] = __builtin_amdgcn_mfma_f32_16x16x32_bf16(AL[mt], BH[j], acc[mt][j], 0, 0, 0); } \
} while (0)

    LOADF(ah0, al0, bh0, bl0, 0);
    for (int kt = 0; kt < KT; kt += 2) {
        LOADF(ah1, al1, bh1, bl1, kt + 1);
        MFMAS(ah0, al0, bh0, bl0);
        if (kt + 2 < KT) LOADF(ah0, al0, bh0, bl0, kt + 2);
        MFMAS(ah1, al1, bh1, bl1);
    }
#undef LOADF
#undef MFMAS

    const int cl = l & 15;
    #pragma unroll
    for (int j = 0; j < 4; ++j) {
        const float bv = bias[(nt0 + j) * 16 + cl];
        #pragma unroll
        for (int mt = 0; mt < 4; ++mt) {
            f32x4 o = acc[mt][j];
            o[0] += bv; o[1] += bv; o[2] += bv; o[3] += bv;
            *(f32x4*)(out + ((((size_t)t * 64 + nt0 + j) * 4 + mt) * 64 + l) * 4) = o;
        }
    }
}

// ---------------------------------------------------------------------------
// Recurrence kernel, dual-mode:
//   coop mode  : launched ONCE via hipLaunchCooperativeKernel with [s0,s1)=[0,32);
//                steps separated by cg::this_grid().sync(); c/mx live in regs.
//   fallback   : launched 32x with [s,s+1); kernel boundary = sync; c/mx
//                round-trip a coalesced f32x4 global buffer.
// Grid = 224 WGs: (run rid, col-quarter q). Weights in VGPRs.
// run ids: 0 L1 fwd full | 1 L1 bwd full | 2..26 bwd prefix len 1..25 |
//          27..51 fwd suffix len 1..25 | 52..55 L2 (r2f,r2b,r3f,r3b)
// ---------------------------------------------------------------------------
__global__ __launch_bounds__(256, 1) void lstm_runs_k(
    const int s0, const int s1,
    const float* __restrict__ xgfP, const float* __restrict__ xgbP,
    const float* __restrict__ xg2P,
    const u16* __restrict__ Whi, const u16* __restrict__ Wlo,
    u16* __restrict__ hHi, u16* __restrict__ hLo,
    float* __restrict__ c_st, float* __restrict__ mx_st,
    float* __restrict__ out_pre, float* __restrict__ out_suf,
    float* __restrict__ r4buf)
{
    __shared__ u16 hh[16384];   // 32 KB: h hi, A-frag-linear
    __shared__ u16 hl[16384];   // 32 KB: h lo

    const int wg  = blockIdx.x;
    const int rid = wg >> 2;
    const int q   = wg & 3;
    const int tid = threadIdx.x;
    const int w   = tid >> 6;
    const int l   = tid & 63;
    const bool coop = (s1 - s0) > 1;

    const float* xg; int wmat, t0, dt, ns, mode, len = 0, part = 0;
    if (rid == 0)      { mode = 0; ns = 32; t0 = 0;  dt = 1;  xg = xgfP; wmat = 0; }
    else if (rid == 1) { mode = 1; ns = 32; t0 = 31; dt = -1; xg = xgbP; wmat = 1; }
    else if (rid < 27) { mode = 2; len = rid - 1;  ns = len;      t0 = len - 1; dt = -1; xg = xgbP; wmat = 1; }
    else if (rid < 52) { mode = 3; len = rid - 26; ns = 32 - len; t0 = len;     dt = 1;  xg = xgfP; wmat = 0; }
    else { mode = 4; part = rid - 52; ns = 32;
           xg = xg2P + (size_t)part * ((size_t)BB * TT * ZN);
           wmat = 2 + (part & 1); if (part & 1) { t0 = 31; dt = -1; } else { t0 = 0; dt = 1; } }

    if (!coop && s0 >= ns) return;

    // ---- weights -> registers (once per launch) ----
    bfrag WH[8][4], WL[8][4];
    if (s0 > 0 || s1 > 1) {
        const u16* WHp = Whi + (size_t)wmat * 262144;
        const u16* WLp = Wlo + (size_t)wmat * 262144;
        #pragma unroll
        for (int kt = 0; kt < 8; ++kt)
            #pragma unroll
            for (int g = 0; g < 4; ++g) {
                const size_t ob = (((size_t)kt * 64 + g * 16 + q * 4 + w) * 64 + l) * 8;
                WH[kt][g] = *(const bfrag*)(WHp + ob);
                WL[kt][g] = *(const bfrag*)(WLp + ob);
            }
    }

    const int cl = l & 15, rsub = (l >> 4) << 2;
    const int hc = q * 64 + w * 16 + cl;
    const int kt2 = hc >> 5, i2 = hc & 7, lhi = (hc >> 3) & 3;
    const size_t HRUN = 16384, HSLOT = 56 * HRUN;
    const size_t stBase = ((size_t)wg * 256 + tid) * 16;   // c/mx frag slot (f32)

    float c[4][4], mx[4][4];
    if (s0 == 0) {
        #pragma unroll
        for (int a = 0; a < 4; ++a)
            #pragma unroll
            for (int b = 0; b < 4; ++b) { c[a][b] = 0.f; mx[a][b] = -3.4e38f; }
    } else {
        #pragma unroll
        for (int mt = 0; mt < 4; ++mt) {
            const f32x4 cv = *(const f32x4*)(c_st  + stBase + mt * 4);
            const f32x4 mv = *(const f32x4*)(mx_st + stBase + mt * 4);
            #pragma unroll
            for (int r = 0; r < 4; ++r) { c[mt][r] = cv[r]; mx[mt][r] = mv[r]; }
        }
    }

    for (int s = s0; s < s1; ++s) {
        if (coop && s > s0) cg::this_grid().sync();
        if (s >= ns) continue;
        const int t = t0 + dt * s;

        f32x4 acc[4][4];
        #pragma unroll
        for (int a = 0; a < 4; ++a)
            #pragma unroll
            for (int b = 0; b < 4; ++b) acc[a][b] = (f32x4){0.f, 0.f, 0.f, 0.f};

        if (s > 0) {
            __syncthreads();   // prior-step LDS reads complete before overwrite
            const uint4* srcH = (const uint4*)(hHi + (size_t)(s & 1) * HSLOT + (size_t)rid * HRUN);
            const uint4* srcL = (const uint4*)(hLo + (size_t)(s & 1) * HSLOT + (size_t)rid * HRUN);
            uint4* dH = (uint4*)hh; uint4* dL = (uint4*)hl;
            #pragma unroll
            for (int p = 0; p < 8; ++p) {
                dH[tid + 256 * p] = srcH[tid + 256 * p];
                dL[tid + 256 * p] = srcL[tid + 256 * p];
            }
            __syncthreads();

            #pragma unroll
            for (int kt = 0; kt < 8; ++kt) {
                bfrag ah[4], al[4];
                #pragma unroll
                for (int mt = 0; mt < 4; ++mt) {
                    const int oa = ((kt * 4 + mt) * 64 + l) * 8;
                    ah[mt] = *(const bfrag*)&hh[oa];
                    al[mt] = *(const bfrag*)&hl[oa];
                }
                #pragma unroll
                for (int mt = 0; mt < 4; ++mt)
                    #pragma unroll
                    for (int g = 0; g < 4; ++g) {
                        acc[mt][g] = __builtin_amdgcn_mfma_f32_16x16x32_bf16(ah[mt], WH[kt][g], acc[mt][g], 0, 0, 0);
                        acc[mt][g] = __builtin_amdgcn_mfma_f32_16x16x32_bf16(ah[mt], WL[kt][g], acc[mt][g], 0, 0, 0);
                        acc[mt][g] = __builtin_amdgcn_mfma_f32_16x16x32_bf16(al[mt], WH[kt][g], acc[mt][g], 0, 0, 0);
                    }
            }
        }

        // ------------------ gates + state update + outputs ------------------
        u16* hWH = hHi + (size_t)((s + 1) & 1) * HSLOT + (size_t)rid * HRUN;
        u16* hWL = hLo + (size_t)((s + 1) & 1) * HSLOT + (size_t)rid * HRUN;

        #pragma unroll
        for (int mt = 0; mt < 4; ++mt) {
            f32x4 xv[4];
            #pragma unroll
            for (int g = 0; g < 4; ++g)
                xv[g] = *(const f32x4*)(xg + ((((size_t)t * 64 + g * 16 + q * 4 + w) * 4 + mt) * 64 + l) * 4);
            #pragma unroll
            for (int reg = 0; reg < 4; ++reg) {
                const int row = mt * 16 + rsub + reg;
                const float zi = acc[mt][0][reg] + xv[0][reg];
                const float zf = acc[mt][1][reg] + xv[1][reg];
                const float zg = acc[mt][2][reg] + xv[2][reg];
                const float zo = acc[mt][3][reg] + xv[3][reg];
                const float c2 = sigm_(zf) * c[mt][reg] + sigm_(zi) * tanh_(zg);
                const float h2 = sigm_(zo) * tanh_(c2);
                c[mt][reg] = c2;
                const float m2 = fmaxf(mx[mt][reg], h2);
                mx[mt][reg] = m2;

                const u16 uh = f2bf(h2);
                const u16 ul = f2bf(h2 - bf2f(uh));
                const size_t hidx = ((size_t)(kt2 * 4 + mt) * 64 + lhi * 16 + rsub + reg) * 8 + i2;
                hWH[hidx] = uh;
                hWL[hidx] = ul;

                if (mode == 0) {
                    if (t <= 24)
                        out_pre[((size_t)t * BB + row) * (2 * HH) + hc] = m2;
                } else if (mode == 1) {
                    if (t >= 1 && t <= 25)
                        out_suf[((size_t)(t - 1) * BB + row) * (2 * HH) + HH + hc] = m2;
                } else if (mode == 2) {
                    if (s == ns - 1)
                        out_pre[((size_t)(len - 1) * BB + row) * (2 * HH) + HH + hc] = m2;
                } else if (mode == 3) {
                    if (s == ns - 1)
                        out_suf[((size_t)(len - 1) * BB + row) * (2 * HH) + hc] = m2;
                } else {
                    r4buf[((size_t)row * TT + t) * ZN + part * HH + hc] = h2;
                }
            }
        }
    }

    // persist c/mx only in fallback mode (next launch reloads)
    if (!coop && s1 < TT) {
        #pragma unroll
        for (int mt = 0; mt < 4; ++mt) {
            f32x4 cv, mv;
            #pragma unroll
            for (int r = 0; r < 4; ++r) { cv[r] = c[mt][r]; mv[r] = mx[mt][r]; }
            *(f32x4*)(c_st  + stBase + mt * 4) = cv;
            *(f32x4*)(mx_st + stBase + mt * 4) = mv;
        }
    }
}

// ---------------------------------------------------------------------------
extern "C" void kernel_launch(void* const* d_in, const int* in_sizes, int n_in,
                              void* d_out, int out_size, void* d_ws, size_t ws_size,
                              hipStream_t stream)
{
    const float* x    = (const float*)d_in[0];
    const float* wif  = (const float*)d_in[1];
    const float* whf  = (const float*)d_in[2];
    const float* bf   = (const float*)d_in[3];
    const float* wib  = (const float*)d_in[4];
    const float* whb  = (const float*)d_in[5];
    const float* bb   = (const float*)d_in[6];
    const float* w2if = (const float*)d_in[7];
    const float* w2hf = (const float*)d_in[8];
    const float* b2f  = (const float*)d_in[9];
    const float* w2ib = (const float*)d_in[10];
    const float* w2hb = (const float*)d_in[11];
    const float* b2b  = (const float*)d_in[12];
    const float* wl   = (const float*)d_in[13];
    const float* bl   = (const float*)d_in[14];

    const size_t XG = (size_t)BB * TT * ZN;          // 2,097,152 floats
    float* xgfP  = (float*)d_ws;
    float* xgbP  = xgfP + XG;
    float* xg2P  = xgbP + XG;                        // 4 consecutive arrays
    float* r4    = xg2P + 4 * XG;
    float* c_st  = r4 + XG;                          // 224*256*16 floats
    float* mx_st = c_st + (size_t)224 * 256 * 16;

    u16* p = (u16*)(mx_st + (size_t)224 * 256 * 16);
    u16* WhiR = p;  p += (size_t)4 * 262144;
    u16* WloR = p;  p += (size_t)4 * 262144;
    u16* hHi  = p;  p += (size_t)2 * 56 * 16384;
    u16* hLo  = p;  p += (size_t)2 * 56 * 16384;
    u16* xAh  = p;  p += (size_t)2048 * 512;
    u16* xAl  = p;  p += (size_t)2048 * 512;
    u16* r4Ah = p;  p += (size_t)2048 * 1024;
    u16* r4Al = p;  p += (size_t)2048 * 1024;
    u16* wifBh = p; p += (size_t)1024 * 512;
    u16* wifBl = p; p += (size_t)1024 * 512;
    u16* wibBh = p; p += (size_t)1024 * 512;
    u16* wibBl = p; p += (size_t)1024 * 512;
    u16* w2ifBh = p; p += (size_t)1024 * 256;
    u16* w2ifBl = p; p += (size_t)1024 * 256;
    u16* w2ibBh = p; p += (size_t)1024 * 256;
    u16* w2ibBl = p; p += (size_t)1024 * 256;
    u16* wlBh = p;  p += (size_t)512 * 1024;
    u16* wlBl = p;  p += (size_t)512 * 1024;

    float* outp    = (float*)d_out;
    float* out_pre = outp + (size_t)BB * TT * OO;
    float* out_suf = out_pre + (size_t)NPRE * BB * (2 * HH);

    // 1. fragment preps
    prep_frag<<<dim3(128, 8),  256, 0, stream>>>(whf,  HH, WhiR + 0 * 262144, WloR + 0 * 262144);
    prep_frag<<<dim3(128, 8),  256, 0, stream>>>(whb,  HH, WhiR + 1 * 262144, WloR + 1 * 262144);
    prep_frag<<<dim3(128, 8),  256, 0, stream>>>(w2hf, HH, WhiR + 2 * 262144, WloR + 2 * 262144);
    prep_frag<<<dim3(128, 8),  256, 0, stream>>>(w2hb, HH, WhiR + 3 * 262144, WloR + 3 * 262144);
    prep_x_tmajor<<<dim3(256, 16), 256, 0, stream>>>(x, xAh, xAl);           // t-major A
    prep_frag<<<dim3(128, 16), 256, 0, stream>>>(wif,  II, wifBh, wifBl);    // T=64,  K=512
    prep_frag<<<dim3(128, 16), 256, 0, stream>>>(wib,  II, wibBh, wibBl);
    prep_frag<<<dim3(128, 8),  256, 0, stream>>>(w2if, HH, w2ifBh, w2ifBl);  // T=64,  K=256
    prep_frag<<<dim3(128, 8),  256, 0, stream>>>(w2ib, HH, w2ibBh, w2ibBl);
    prep_frag<<<dim3(64, 32),  256, 0, stream>>>(wl,   ZN, wlBh, wlBl);      // T=32,  K=1024

    // 2. input-gate activation GEMMs -> fragment-layout xgP buffers
    gemm_xg<<<dim3(4, 32), 256, 0, stream>>>(xAh, xAl, 0, wifBh,  wifBl,  bf,  xgfP,        16);
    gemm_xg<<<dim3(4, 32), 256, 0, stream>>>(xAh, xAl, 0, wibBh,  wibBl,  bb,  xgbP,        16);
    gemm_xg<<<dim3(4, 32), 256, 0, stream>>>(xAh, xAl, 0, w2ifBh, w2ifBl, b2f, xg2P + 0*XG,  8);
    gemm_xg<<<dim3(4, 32), 256, 0, stream>>>(xAh, xAl, 0, w2ibBh, w2ibBl, b2b, xg2P + 1*XG,  8);
    gemm_xg<<<dim3(4, 32), 256, 0, stream>>>(xAh, xAl, 8, w2ifBh, w2ifBl, b2f, xg2P + 2*XG,  8);
    gemm_xg<<<dim3(4, 32), 256, 0, stream>>>(xAh, xAl, 8, w2ibBh, w2ibBl, b2b, xg2P + 3*XG,  8);

    // 3. recurrence: try one cooperative launch (grid.sync between steps);
    //    on failure fall back to 32 per-step launches (kernel-boundary sync).
    {
        int cs0 = 0, cs1 = TT;
        const float* a_xgf = xgfP; const float* a_xgb = xgbP; const float* a_xg2 = xg2P;
        const u16* a_whi = WhiR; const u16* a_wlo = WloR;
        u16* a_hhi = hHi; u16* a_hlo = hLo;
        float* a_cst = c_st; float* a_mx = mx_st;
        float* a_pre = out_pre; float* a_suf = out_suf; float* a_r4 = r4;
        void* cargs[] = { (void*)&cs0, (void*)&cs1,
                          (void*)&a_xgf, (void*)&a_xgb, (void*)&a_xg2,
                          (void*)&a_whi, (void*)&a_wlo,
                          (void*)&a_hhi, (void*)&a_hlo,
                          (void*)&a_cst, (void*)&a_mx,
                          (void*)&a_pre, (void*)&a_suf, (void*)&a_r4 };
        hipError_t ce = hipLaunchCooperativeKernel((const void*)lstm_runs_k,
                                                   dim3(224), dim3(256), cargs, 0, stream);
        if (ce != hipSuccess) {
            for (int s = 0; s < TT; ++s)
                lstm_runs_k<<<dim3(224), dim3(256), 0, stream>>>(s, s + 1,
                    xgfP, xgbP, xg2P, WhiR, WloR, hHi, hLo, c_st, mx_st,
                    out_pre, out_suf, r4);
        }
    }

    // 4. final projection: output = r4 @ wl^T + bl
    prep_frag<<<dim3(256, 32), 256, 0, stream>>>(r4, ZN, r4Ah, r4Al);        // T=128, K=1024
    gemm_mfma<<<dim3(2, 32), 256, 0, stream>>>(r4Ah, r4Al, 128, 0, wlBh, wlBl, 32, bl, outp, OO, 32);
}

// Round 6
// 741.148 us; speedup vs baseline: 1.9650x; 1.9650x over previous
//
#include <hip/hip_runtime.h>
#include <math.h>

#define BB 64
#define TT 32
#define II 512
#define HH 256
#define ZN 1024   // 4*H
#define OO 512
#define NPRE 25

typedef unsigned short u16;
typedef short bfrag __attribute__((ext_vector_type(8)));   // 8 bf16 (4 VGPRs)
typedef float f32x4 __attribute__((ext_vector_type(4)));

__device__ __forceinline__ float sigm_(float x) { return 1.f / (1.f + __expf(-x)); }
__device__ __forceinline__ float tanh_(float x) { return 1.f - 2.f / (__expf(2.f * x) + 1.f); }

__device__ __forceinline__ u16 f2bf(float x) {
    union { float f; unsigned u; } v; v.f = x;
    unsigned r = v.u + 0x7fffu + ((v.u >> 16) & 1u);   // RNE
    return (u16)(r >> 16);
}
__device__ __forceinline__ float bf2f(u16 b) {
    union { unsigned u; float f; } v; v.u = ((unsigned)b) << 16; return v.f;
}

// ---------------------------------------------------------------------------
// Fragment preps: fp32 [D][ld] row-major -> fragment-linear bf16 hi/lo.
//   idx = ((kt*T + t)*64 + l)*8 + i ; d = t*16 + (l&15) ; k = kt*32 + ((l>>4)<<3) + i
// ---------------------------------------------------------------------------
__global__ __launch_bounds__(256) void prep_frag(      // generic (wl, r4)
    const float* __restrict__ src, int ld,
    u16* __restrict__ hi, u16* __restrict__ lo)
{
    const int T  = gridDim.x >> 1;
    const int e2 = blockIdx.x * 256 + threadIdx.x;
    const int kt = blockIdx.y;
    const int i = e2 & 7, l = (e2 >> 3) & 63, t = e2 >> 9;
    const int d = t * 16 + (l & 15);
    const int k = kt * 32 + ((l >> 4) << 3) + i;
    const float v = src[(size_t)d * ld + k];
    const u16 h = f2bf(v);
    const size_t o = (size_t)kt * ((size_t)T * 512) + e2;
    hi[o] = h;
    lo[o] = f2bf(v - bf2f(h));
}

// six [1024][256] matrices fused: whf, whb, w2hf, w2hb, w2if, w2ib
__global__ __launch_bounds__(256) void prep_w8(
    const float* __restrict__ s0, const float* __restrict__ s1,
    const float* __restrict__ s2, const float* __restrict__ s3,
    const float* __restrict__ s4, const float* __restrict__ s5,
    u16* __restrict__ hi, u16* __restrict__ lo)
{
    const int z = blockIdx.z;
    const float* src = (z == 0) ? s0 : (z == 1) ? s1 : (z == 2) ? s2 :
                       (z == 3) ? s3 : (z == 4) ? s4 : s5;
    const int e2 = blockIdx.x * 256 + threadIdx.x;     // T=64 -> 2T=128 blocks
    const int kt = blockIdx.y;                          // 0..7
    const int i = e2 & 7, l = (e2 >> 3) & 63, t = e2 >> 9;
    const int d = t * 16 + (l & 15);
    const int k = kt * 32 + ((l >> 4) << 3) + i;
    const float v = src[(size_t)d * HH + k];
    const u16 h = f2bf(v);
    const size_t o = (size_t)z * 262144 + (size_t)kt * 32768 + e2;
    hi[o] = h;
    lo[o] = f2bf(v - bf2f(h));
}

// two [1024][512] matrices fused: wif, wib
__global__ __launch_bounds__(256) void prep_w16(
    const float* __restrict__ s0, const float* __restrict__ s1,
    u16* __restrict__ hi, u16* __restrict__ lo)
{
    const int z = blockIdx.z;
    const float* src = z ? s1 : s0;
    const int e2 = blockIdx.x * 256 + threadIdx.x;     // T=64
    const int kt = blockIdx.y;                          // 0..15
    const int i = e2 & 7, l = (e2 >> 3) & 63, t = e2 >> 9;
    const int d = t * 16 + (l & 15);
    const int k = kt * 32 + ((l >> 4) << 3) + i;
    const float v = src[(size_t)d * II + k];
    const u16 h = f2bf(v);
    const size_t o = (size_t)z * 524288 + (size_t)kt * 32768 + e2;
    hi[o] = h;
    lo[o] = f2bf(v - bf2f(h));
}

// x in t-major A-frag layout: m = t*64 + row. K=512, MT=128, KT=16.
__global__ __launch_bounds__(256) void prep_x_tmajor(
    const float* __restrict__ x, u16* __restrict__ hi, u16* __restrict__ lo)
{
    const int e2 = blockIdx.x * 256 + threadIdx.x;
    const int kt = blockIdx.y;
    const int i = e2 & 7, l = (e2 >> 3) & 63, mt = e2 >> 9;
    const int d = mt * 16 + (l & 15);
    const int t = d >> 6, row = d & 63;
    const int k = kt * 32 + ((l >> 4) << 3) + i;
    const float v = x[((size_t)row * TT + t) * II + k];
    const u16 h = f2bf(v);
    const size_t o = (size_t)kt * 65536 + e2;
    hi[o] = h;
    lo[o] = f2bf(v - bf2f(h));
}

// ---------------------------------------------------------------------------
// Register-fragment MFMA GEMM (bf16 x3 ~= fp32), row-major output (tail proj).
// ---------------------------------------------------------------------------
__global__ __launch_bounds__(256) void gemm_mfma(
    const u16* __restrict__ Ahi, const u16* __restrict__ Alo, const int MT, const int kt0,
    const u16* __restrict__ Bhi, const u16* __restrict__ Blo, const int NT,
    const float* __restrict__ bias,
    float* __restrict__ C, const int ldc, const int KT)
{
    const int tid = threadIdx.x;
    const int w = tid >> 6, l = tid & 63;
    const int mt0 = blockIdx.y * 4;
    const int nt0 = blockIdx.x * 16 + w * 4;

    f32x4 acc[4][4];
    #pragma unroll
    for (int a = 0; a < 4; ++a)
        #pragma unroll
        for (int b = 0; b < 4; ++b) acc[a][b] = (f32x4){0.f, 0.f, 0.f, 0.f};

    bfrag ah0[4], al0[4], bh0[4], bl0[4];
    bfrag ah1[4], al1[4], bh1[4], bl1[4];

#define LOADF(AH, AL, BH, BL, KIDX) do {                                          \
    const int kk_ = (KIDX);                                                      \
    _Pragma("unroll") for (int mt = 0; mt < 4; ++mt) {                            \
        const size_t oa = (((size_t)(kt0 + kk_) * MT + mt0 + mt) * 64 + l) * 8;   \
        AH[mt] = *(const bfrag*)(Ahi + oa); AL[mt] = *(const bfrag*)(Alo + oa); } \
    _Pragma("unroll") for (int j = 0; j < 4; ++j) {                               \
        const size_t ob = (((size_t)kk_ * NT + nt0 + j) * 64 + l) * 8;            \
        BH[j] = *(const bfrag*)(Bhi + ob); BL[j] = *(const bfrag*)(Blo + ob); }   \
} while (0)

#define MFMAS(AH, AL, BH, BL) do {                                                \
    _Pragma("unroll") for (int mt = 0; mt < 4; ++mt)                              \
    _Pragma("unroll") for (int j = 0; j < 4; ++j) {                               \
        acc[mt][j] = __builtin_amdgcn_mfma_f32_16x16x32_bf16(AH[mt], BH[j], acc[mt][j], 0, 0, 0); \
        acc[mt][j] = __builtin_amdgcn_mfma_f32_16x16x32_bf16(AH[mt], BL[j], acc[mt][j], 0, 0, 0); \
        acc[mt][j] = __builtin_amdgcn_mfma_f32_16x16x32_bf16(AL[mt], BH[j], acc[mt][j], 0, 0, 0); } \
} while (0)

    LOADF(ah0, al0, bh0, bl0, 0);
    for (int kt = 0; kt < KT; kt += 2) {
        LOADF(ah1, al1, bh1, bl1, kt + 1);
        MFMAS(ah0, al0, bh0, bl0);
        if (kt + 2 < KT) LOADF(ah0, al0, bh0, bl0, kt + 2);
        MFMAS(ah1, al1, bh1, bl1);
    }

    const int rsub = (l >> 4) << 2;
    #pragma unroll
    for (int j = 0; j < 4; ++j) {
        const int col = (nt0 + j) * 16 + (l & 15);
        const float bv = bias[col];
        #pragma unroll
        for (int mt = 0; mt < 4; ++mt)
            #pragma unroll
            for (int reg = 0; reg < 4; ++reg)
                C[(size_t)((mt0 + mt) * 16 + rsub + reg) * ldc + col] = acc[mt][j][reg] + bv;
    }
#undef LOADF
#undef MFMAS
}

// ---------------------------------------------------------------------------
// xg-producer GEMM, z-fused: A = x t-major frags (blockIdx.y = t).
// z selects B (z&1, stride bstride), kt0 = (z>>1)*kt0h, bias (z&1), out + z*XG.
// Output in MFMA C/D fragment layout:
//   xgP[(((t*64 + nt)*4 + mt)*64 + l)*4 + reg]
// ---------------------------------------------------------------------------
__global__ __launch_bounds__(256) void gemm_xg(
    const u16* __restrict__ Ahi, const u16* __restrict__ Alo, const int kt0h,
    const u16* __restrict__ Bhi0, const u16* __restrict__ Blo0, const size_t bstride,
    const float* __restrict__ bias_even, const float* __restrict__ bias_odd,
    float* __restrict__ out0, const int KT)
{
    const int MT = 128, NT = 64;
    const int z = blockIdx.z;
    const int kt0 = (z >> 1) * kt0h;
    const u16* Bhi = Bhi0 + (size_t)(z & 1) * bstride;
    const u16* Blo = Blo0 + (size_t)(z & 1) * bstride;
    const float* bias = (z & 1) ? bias_odd : bias_even;
    float* out = out0 + (size_t)z * ((size_t)BB * TT * ZN);

    const int tid = threadIdx.x;
    const int w = tid >> 6, l = tid & 63;
    const int t = blockIdx.y;
    const int mt0 = t * 4;
    const int nt0 = blockIdx.x * 16 + w * 4;

    f32x4 acc[4][4];
    #pragma unroll
    for (int a = 0; a < 4; ++a)
        #pragma unroll
        for (int b = 0; b < 4; ++b) acc[a][b] = (f32x4){0.f, 0.f, 0.f, 0.f};

    bfrag ah0[4], al0[4], bh0[4], bl0[4];
    bfrag ah1[4], al1[4], bh1[4], bl1[4];

#define LOADF(AH, AL, BH, BL, KIDX) do {                                          \
    const int kk_ = (KIDX);                                                      \
    _Pragma("unroll") for (int mt = 0; mt < 4; ++mt) {                            \
        const size_t oa = (((size_t)(kt0 + kk_) * MT + mt0 + mt) * 64 + l) * 8;   \
        AH[mt] = *(const bfrag*)(Ahi + oa); AL[mt] = *(const bfrag*)(Alo + oa); } \
    _Pragma("unroll") for (int j = 0; j < 4; ++j) {                               \
        const size_t ob = (((size_t)kk_ * NT + nt0 + j) * 64 + l) * 8;            \
        BH[j] = *(const bfrag*)(Bhi + ob); BL[j] = *(const bfrag*)(Blo + ob); }   \
} while (0)

#define MFMAS(AH, AL, BH, BL) do {                                                \
    _Pragma("unroll") for (int mt = 0; mt < 4; ++mt)                              \
    _Pragma("unroll") for (int j = 0; j < 4; ++j) {                               \
        acc[mt][j] = __builtin_amdgcn_mfma_f32_16x16x32_bf16(AH[mt], BH[j], acc[mt][j], 0, 0, 0); \
        acc[mt][j] = __builtin_amdgcn_mfma_f32_16x16x32_bf16(AH[mt], BL[j], acc[mt][j], 0, 0, 0); \
        acc[mt][j] = __builtin_amdgcn_mfma_f32_16x16x32_bf16(AL[mt], BH[j], acc[mt][j], 0, 0, 0); } \
} while (0)

    LOADF(ah0, al0, bh0, bl0, 0);
    for (int kt = 0; kt < KT; kt += 2) {
        LOADF(ah1, al1, bh1, bl1, kt + 1);
        MFMAS(ah0, al0, bh0, bl0);
        if (kt + 2 < KT) LOADF(ah0, al0, bh0, bl0, kt + 2);
        MFMAS(ah1, al1, bh1, bl1);
    }
#undef LOADF
#undef MFMAS

    const int cl = l & 15;
    #pragma unroll
    for (int j = 0; j < 4; ++j) {
        const float bv = bias[(nt0 + j) * 16 + cl];
        #pragma unroll
        for (int mt = 0; mt < 4; ++mt) {
            f32x4 o = acc[mt][j];
            o[0] += bv; o[1] += bv; o[2] += bv; o[3] += bv;
            *(f32x4*)(out + ((((size_t)t * 64 + nt0 + j) * 4 + mt) * 64 + l) * 4) = o;
        }
    }
}

// ---------------------------------------------------------------------------
// Recurrence. coop mode: ONE cooperative launch, [s0,s1)=[0,32); steps chained
// by a PER-RUN 4-WG barrier (agent-scope acquire/release). ALL cross-WG h data
// moves via agent-scope u32 atomics (packed bf16 hi|lo) -- bypasses the
// per-XCD L2s (round-4 bug: normal loads read stale L2; round-5 grid.sync fix
// thrashed all caches). fallback: 32 single-step launches, c/mx via global.
// h packed layout per run-slot (16384 u32):
//   widx = q*4096 + (mt*4+reg)*256 + w*64 + l  (writer-coalesced)
// run ids: 0 L1 fwd full | 1 L1 bwd full | 2..26 bwd prefix len 1..25 |
//          27..51 fwd suffix len 1..25 | 52..55 L2 (r2f,r2b,r3f,r3b)
// ---------------------------------------------------------------------------
__global__ __launch_bounds__(256, 1) void lstm_runs_k(
    const int s0, const int s1,
    const float* __restrict__ xgfP, const float* __restrict__ xgbP,
    const float* __restrict__ xg2P,
    const u16* __restrict__ Whi, const u16* __restrict__ Wlo,
    unsigned* __restrict__ hPk, unsigned* __restrict__ bar,
    float* __restrict__ c_st, float* __restrict__ mx_st,
    float* __restrict__ out_pre, float* __restrict__ out_suf,
    float* __restrict__ r4buf)
{
    __shared__ u16 hh[16384];   // 32 KB: h hi, A-frag-linear
    __shared__ u16 hl[16384];   // 32 KB: h lo

    const int wg  = blockIdx.x;
    const int rid = wg >> 2;
    const int q   = wg & 3;
    const int tid = threadIdx.x;
    const int w   = tid >> 6;
    const int l   = tid & 63;
    const bool coop = (s1 - s0) > 1;

    const float* xg; int wmat, t0, dt, ns, mode, len = 0, part = 0;
    if (rid == 0)      { mode = 0; ns = 32; t0 = 0;  dt = 1;  xg = xgfP; wmat = 0; }
    else if (rid == 1) { mode = 1; ns = 32; t0 = 31; dt = -1; xg = xgbP; wmat = 1; }
    else if (rid < 27) { mode = 2; len = rid - 1;  ns = len;      t0 = len - 1; dt = -1; xg = xgbP; wmat = 1; }
    else if (rid < 52) { mode = 3; len = rid - 26; ns = 32 - len; t0 = len;     dt = 1;  xg = xgfP; wmat = 0; }
    else { mode = 4; part = rid - 52; ns = 32;
           xg = xg2P + (size_t)part * ((size_t)BB * TT * ZN);
           wmat = 2 + (part & 1); if (part & 1) { t0 = 31; dt = -1; } else { t0 = 0; dt = 1; } }

    if (!coop && s0 >= ns) return;

    // ---- weights -> registers (once per launch) ----
    bfrag WH[8][4], WL[8][4];
    if (s0 > 0 || s1 > 1) {
        const u16* WHp = Whi + (size_t)wmat * 262144;
        const u16* WLp = Wlo + (size_t)wmat * 262144;
        #pragma unroll
        for (int kt = 0; kt < 8; ++kt)
            #pragma unroll
            for (int g = 0; g < 4; ++g) {
                const size_t ob = (((size_t)kt * 64 + g * 16 + q * 4 + w) * 64 + l) * 8;
                WH[kt][g] = *(const bfrag*)(WHp + ob);
                WL[kt][g] = *(const bfrag*)(WLp + ob);
            }
    }

    const int cl = l & 15, rsub = (l >> 4) << 2;
    const int hc = q * 64 + w * 16 + cl;
    const int wbase = q * 4096 + w * 64 + l;               // packed-h write base
    const size_t stBase = ((size_t)wg * 256 + tid) * 16;   // c/mx slot (fallback)

    float c[4][4], mx[4][4];
    if (s0 == 0) {
        #pragma unroll
        for (int a = 0; a < 4; ++a)
            #pragma unroll
            for (int b = 0; b < 4; ++b) { c[a][b] = 0.f; mx[a][b] = -3.4e38f; }
    } else {
        #pragma unroll
        for (int mt = 0; mt < 4; ++mt) {
            const f32x4 cv = *(const f32x4*)(c_st  + stBase + mt * 4);
            const f32x4 mv = *(const f32x4*)(mx_st + stBase + mt * 4);
            #pragma unroll
            for (int r = 0; r < 4; ++r) { c[mt][r] = cv[r]; mx[mt][r] = mv[r]; }
        }
    }

    for (int s = s0; s < s1; ++s) {
        if (s >= ns) break;
        const int t = t0 + dt * s;

        f32x4 acc[4][4];
        #pragma unroll
        for (int a = 0; a < 4; ++a)
            #pragma unroll
            for (int b = 0; b < 4; ++b) acc[a][b] = (f32x4){0.f, 0.f, 0.f, 0.f};

        if (s > 0) {
            if (coop && tid == 0) {
                while (__hip_atomic_load(&bar[rid * 32], __ATOMIC_ACQUIRE,
                                         __HIP_MEMORY_SCOPE_AGENT) < (unsigned)(4 * s)) {}
            }
            __syncthreads();   // spin-result broadcast + LDS reuse fence

            // stage h (agent-coherent atomic loads, 4 chunks x 16 in flight)
            const unsigned* srcP = hPk + ((size_t)(s & 1) * 56 + rid) * 16384;
            #pragma unroll
            for (int pc = 0; pc < 4; ++pc) {
                unsigned vv[16];
                #pragma unroll
                for (int j = 0; j < 16; ++j)
                    vv[j] = __hip_atomic_load(srcP + (pc * 16 + j) * 256 + tid,
                                              __ATOMIC_RELAXED, __HIP_MEMORY_SCOPE_AGENT);
                #pragma unroll
                for (int j = 0; j < 16; ++j) {
                    const int widx = (pc * 16 + j) * 256 + tid;
                    const int cl_ = widx & 15;
                    const int rr_ = (widx >> 4) & 3;
                    const int w_  = (widx >> 6) & 3;
                    const int mr_ = (widx >> 8) & 15;
                    const int q_  = widx >> 12;
                    const int col = q_ * 64 + w_ * 16 + cl_;
                    const int fi  = (((col >> 5) * 4 + (mr_ >> 2)) * 64 +
                                     ((col >> 3) & 3) * 16 + rr_ * 4 + (mr_ & 3)) * 8 + (col & 7);
                    hh[fi] = (u16)(vv[j] & 0xffffu);
                    hl[fi] = (u16)(vv[j] >> 16);
                }
            }
            __syncthreads();

            #pragma unroll
            for (int kt = 0; kt < 8; ++kt) {
                bfrag ah[4], al[4];
                #pragma unroll
                for (int mt = 0; mt < 4; ++mt) {
                    const int oa = ((kt * 4 + mt) * 64 + l) * 8;
                    ah[mt] = *(const bfrag*)&hh[oa];
                    al[mt] = *(const bfrag*)&hl[oa];
                }
                #pragma unroll
                for (int mt = 0; mt < 4; ++mt)
                    #pragma unroll
                    for (int g = 0; g < 4; ++g) {
                        acc[mt][g] = __builtin_amdgcn_mfma_f32_16x16x32_bf16(ah[mt], WH[kt][g], acc[mt][g], 0, 0, 0);
                        acc[mt][g] = __builtin_amdgcn_mfma_f32_16x16x32_bf16(ah[mt], WL[kt][g], acc[mt][g], 0, 0, 0);
                        acc[mt][g] = __builtin_amdgcn_mfma_f32_16x16x32_bf16(al[mt], WH[kt][g], acc[mt][g], 0, 0, 0);
                    }
            }
        }

        // ------------------ gates + state update + outputs ------------------
        unsigned* dstP = hPk + ((size_t)((s + 1) & 1) * 56 + rid) * 16384;

        #pragma unroll
        for (int mt = 0; mt < 4; ++mt) {
            f32x4 xv[4];
            #pragma unroll
            for (int g = 0; g < 4; ++g)
                xv[g] = *(const f32x4*)(xg + ((((size_t)t * 64 + g * 16 + q * 4 + w) * 4 + mt) * 64 + l) * 4);
            #pragma unroll
            for (int reg = 0; reg < 4; ++reg) {
                const int row = mt * 16 + rsub + reg;
                const float zi = acc[mt][0][reg] + xv[0][reg];
                const float zf = acc[mt][1][reg] + xv[1][reg];
                const float zg = acc[mt][2][reg] + xv[2][reg];
                const float zo = acc[mt][3][reg] + xv[3][reg];
                const float c2 = sigm_(zf) * c[mt][reg] + sigm_(zi) * tanh_(zg);
                const float h2 = sigm_(zo) * tanh_(c2);
                c[mt][reg] = c2;
                const float m2 = fmaxf(mx[mt][reg], h2);
                mx[mt][reg] = m2;

                const u16 uh = f2bf(h2);
                const u16 ul = f2bf(h2 - bf2f(uh));
                const unsigned pk = (unsigned)uh | ((unsigned)ul << 16);
                __hip_atomic_store(dstP + wbase + (mt * 4 + reg) * 256, pk,
                                   __ATOMIC_RELAXED, __HIP_MEMORY_SCOPE_AGENT);

                if (mode == 0) {
                    if (t <= 24)
                        out_pre[((size_t)t * BB + row) * (2 * HH) + hc] = m2;
                } else if (mode == 1) {
                    if (t >= 1 && t <= 25)
                        out_suf[((size_t)(t - 1) * BB + row) * (2 * HH) + HH + hc] = m2;
                } else if (mode == 2) {
                    if (s == ns - 1)
                        out_pre[((size_t)(len - 1) * BB + row) * (2 * HH) + HH + hc] = m2;
                } else if (mode == 3) {
                    if (s == ns - 1)
                        out_suf[((size_t)(len - 1) * BB + row) * (2 * HH) + hc] = m2;
                } else {
                    r4buf[((size_t)row * TT + t) * ZN + part * HH + hc] = h2;
                }
            }
        }

        // signal end of step s (syncthreads drains all lanes' stores first)
        if (coop && s + 1 < ns) {
            __syncthreads();
            if (tid == 0)
                __hip_atomic_fetch_add(&bar[rid * 32], 1u, __ATOMIC_RELEASE,
                                       __HIP_MEMORY_SCOPE_AGENT);
        }
    }

    // persist c/mx only in fallback mode (next launch reloads)
    if (!coop && s1 < TT) {
        #pragma unroll
        for (int mt = 0; mt < 4; ++mt) {
            f32x4 cv, mv;
            #pragma unroll
            for (int r = 0; r < 4; ++r) { cv[r] = c[mt][r]; mv[r] = mx[mt][r]; }
            *(f32x4*)(c_st  + stBase + mt * 4) = cv;
            *(f32x4*)(mx_st + stBase + mt * 4) = mv;
        }
    }
}

// ---------------------------------------------------------------------------
extern "C" void kernel_launch(void* const* d_in, const int* in_sizes, int n_in,
                              void* d_out, int out_size, void* d_ws, size_t ws_size,
                              hipStream_t stream)
{
    const float* x    = (const float*)d_in[0];
    const float* wif  = (const float*)d_in[1];
    const float* whf  = (const float*)d_in[2];
    const float* bf   = (const float*)d_in[3];
    const float* wib  = (const float*)d_in[4];
    const float* whb  = (const float*)d_in[5];
    const float* bb   = (const float*)d_in[6];
    const float* w2if = (const float*)d_in[7];
    const float* w2hf = (const float*)d_in[8];
    const float* b2f  = (const float*)d_in[9];
    const float* w2ib = (const float*)d_in[10];
    const float* w2hb = (const float*)d_in[11];
    const float* b2b  = (const float*)d_in[12];
    const float* wl   = (const float*)d_in[13];
    const float* bl   = (const float*)d_in[14];

    const size_t XG = (size_t)BB * TT * ZN;          // 2,097,152 floats
    float* xgfP  = (float*)d_ws;
    float* xgbP  = xgfP + XG;
    float* xg2P  = xgbP + XG;                        // 4 consecutive arrays
    float* r4    = xg2P + 4 * XG;
    float* c_st  = r4 + XG;                          // 224*256*16 floats
    float* mx_st = c_st + (size_t)224 * 256 * 16;

    u16* p = (u16*)(mx_st + (size_t)224 * 256 * 16);
    u16* WB8h  = p; p += (size_t)6 * 262144;   // whf,whb,w2hf,w2hb,w2if,w2ib
    u16* WB8l  = p; p += (size_t)6 * 262144;
    u16* WB16h = p; p += (size_t)2 * 524288;   // wif, wib
    u16* WB16l = p; p += (size_t)2 * 524288;
    u16* wlBh  = p; p += (size_t)524288;
    u16* wlBl  = p; p += (size_t)524288;
    u16* xAh   = p; p += (size_t)2048 * 512;
    u16* xAl   = p; p += (size_t)2048 * 512;
    u16* r4Ah  = p; p += (size_t)2048 * 1024;
    u16* r4Al  = p; p += (size_t)2048 * 1024;
    unsigned* hPk = (unsigned*)p;                       // 2 slots x 56 x 16384 u32
    unsigned* bar = hPk + (size_t)2 * 56 * 16384;       // 56 x 32 (padded)

    float* outp    = (float*)d_out;
    float* out_pre = outp + (size_t)BB * TT * OO;
    float* out_suf = out_pre + (size_t)NPRE * BB * (2 * HH);

    // 0. reset per-run barrier counters (capture-safe memset node)
    hipMemsetAsync(bar, 0, (size_t)56 * 32 * sizeof(unsigned), stream);

    // 1. fragment preps (fused)
    prep_w8 <<<dim3(128, 8, 6),  256, 0, stream>>>(whf, whb, w2hf, w2hb, w2if, w2ib, WB8h, WB8l);
    prep_w16<<<dim3(128, 16, 2), 256, 0, stream>>>(wif, wib, WB16h, WB16l);
    prep_frag<<<dim3(64, 32),    256, 0, stream>>>(wl, ZN, wlBh, wlBl);      // T=32, K=1024
    prep_x_tmajor<<<dim3(256, 16), 256, 0, stream>>>(x, xAh, xAl);

    // 2. input-gate activation GEMMs -> fragment-layout xgP buffers (fused)
    gemm_xg<<<dim3(4, 32, 2), 256, 0, stream>>>(xAh, xAl, 0, WB16h, WB16l, 524288,
                                                bf, bb, xgfP, 16);
    gemm_xg<<<dim3(4, 32, 4), 256, 0, stream>>>(xAh, xAl, 8,
                                                WB8h + (size_t)4 * 262144, WB8l + (size_t)4 * 262144, 262144,
                                                b2f, b2b, xg2P, 8);

    // 3. recurrence: one cooperative launch (per-run barriers inside);
    //    fallback to 32 per-step launches if coop launch fails.
    {
        int cs0 = 0, cs1 = TT;
        const float* a_xgf = xgfP; const float* a_xgb = xgbP; const float* a_xg2 = xg2P;
        const u16* a_whi = WB8h; const u16* a_wlo = WB8l;
        unsigned* a_hpk = hPk; unsigned* a_bar = bar;
        float* a_cst = c_st; float* a_mx = mx_st;
        float* a_pre = out_pre; float* a_suf = out_suf; float* a_r4 = r4;
        void* cargs[] = { (void*)&cs0, (void*)&cs1,
                          (void*)&a_xgf, (void*)&a_xgb, (void*)&a_xg2,
                          (void*)&a_whi, (void*)&a_wlo,
                          (void*)&a_hpk, (void*)&a_bar,
                          (void*)&a_cst, (void*)&a_mx,
                          (void*)&a_pre, (void*)&a_suf, (void*)&a_r4 };
        hipError_t ce = hipLaunchCooperativeKernel((const void*)lstm_runs_k,
                                                   dim3(224), dim3(256), cargs, 0, stream);
        if (ce != hipSuccess) {
            for (int s = 0; s < TT; ++s)
                lstm_runs_k<<<dim3(224), dim3(256), 0, stream>>>(s, s + 1,
                    xgfP, xgbP, xg2P, WB8h, WB8l, hPk, bar, c_st, mx_st,
                    out_pre, out_suf, r4);
        }
    }

    // 4. final projection: output = r4 @ wl^T + bl
    prep_frag<<<dim3(256, 32), 256, 0, stream>>>(r4, ZN, r4Ah, r4Al);        // T=128, K=1024
    gemm_mfma<<<dim3(2, 32), 256, 0, stream>>>(r4Ah, r4Al, 128, 0, wlBh, wlBl, 32, bl, outp, OO, 32);
}

// Round 8
// 696.692 us; speedup vs baseline: 2.0904x; 1.0638x over previous
//
#include <hip/hip_runtime.h>
#include <math.h>

#define BB 64
#define TT 32
#define II 512
#define HH 256
#define ZN 1024   // 4*H
#define OO 512
#define NPRE 25

typedef unsigned short u16;
typedef unsigned long long u64;
typedef short bfrag __attribute__((ext_vector_type(8)));   // 8 bf16 (4 VGPRs)
typedef float f32x4 __attribute__((ext_vector_type(4)));

__device__ __forceinline__ float sigm_(float x) { return 1.f / (1.f + __expf(-x)); }
__device__ __forceinline__ float tanh_(float x) { return 1.f - 2.f / (__expf(2.f * x) + 1.f); }

__device__ __forceinline__ u16 f2bf(float x) {
    union { float f; unsigned u; } v; v.f = x;
    unsigned r = v.u + 0x7fffu + ((v.u >> 16) & 1u);   // RNE
    return (u16)(r >> 16);
}
__device__ __forceinline__ float bf2f(u16 b) {
    union { unsigned u; float f; } v; v.u = ((unsigned)b) << 16; return v.f;
}

// ---------------------------------------------------------------------------
// Fragment preps: fp32 [D][ld] row-major -> fragment-linear bf16 hi/lo.
//   idx = ((kt*T + t)*64 + l)*8 + i ; d = t*16 + (l&15) ; k = kt*32 + ((l>>4)<<3) + i
// ---------------------------------------------------------------------------
__global__ __launch_bounds__(256) void prep_frag(      // generic (wl)
    const float* __restrict__ src, int ld,
    u16* __restrict__ hi, u16* __restrict__ lo)
{
    const int T  = gridDim.x >> 1;
    const int e2 = blockIdx.x * 256 + threadIdx.x;
    const int kt = blockIdx.y;
    const int i = e2 & 7, l = (e2 >> 3) & 63, t = e2 >> 9;
    const int d = t * 16 + (l & 15);
    const int k = kt * 32 + ((l >> 4) << 3) + i;
    const float v = src[(size_t)d * ld + k];
    const u16 h = f2bf(v);
    const size_t o = (size_t)kt * ((size_t)T * 512) + e2;
    hi[o] = h;
    lo[o] = f2bf(v - bf2f(h));
}

// six [1024][256] matrices fused: whf, whb, w2hf, w2hb, w2if, w2ib
__global__ __launch_bounds__(256) void prep_w8(
    const float* __restrict__ s0, const float* __restrict__ s1,
    const float* __restrict__ s2, const float* __restrict__ s3,
    const float* __restrict__ s4, const float* __restrict__ s5,
    u16* __restrict__ hi, u16* __restrict__ lo)
{
    const int z = blockIdx.z;
    const float* src = (z == 0) ? s0 : (z == 1) ? s1 : (z == 2) ? s2 :
                       (z == 3) ? s3 : (z == 4) ? s4 : s5;
    const int e2 = blockIdx.x * 256 + threadIdx.x;
    const int kt = blockIdx.y;                          // 0..7
    const int i = e2 & 7, l = (e2 >> 3) & 63, t = e2 >> 9;
    const int d = t * 16 + (l & 15);
    const int k = kt * 32 + ((l >> 4) << 3) + i;
    const float v = src[(size_t)d * HH + k];
    const u16 h = f2bf(v);
    const size_t o = (size_t)z * 262144 + (size_t)kt * 32768 + e2;
    hi[o] = h;
    lo[o] = f2bf(v - bf2f(h));
}

// two [1024][512] matrices fused: wif, wib
__global__ __launch_bounds__(256) void prep_w16(
    const float* __restrict__ s0, const float* __restrict__ s1,
    u16* __restrict__ hi, u16* __restrict__ lo)
{
    const int z = blockIdx.z;
    const float* src = z ? s1 : s0;
    const int e2 = blockIdx.x * 256 + threadIdx.x;
    const int kt = blockIdx.y;                          // 0..15
    const int i = e2 & 7, l = (e2 >> 3) & 63, t = e2 >> 9;
    const int d = t * 16 + (l & 15);
    const int k = kt * 32 + ((l >> 4) << 3) + i;
    const float v = src[(size_t)d * II + k];
    const u16 h = f2bf(v);
    const size_t o = (size_t)z * 524288 + (size_t)kt * 32768 + e2;
    hi[o] = h;
    lo[o] = f2bf(v - bf2f(h));
}

// x in t-major A-frag layout: m = t*64 + row. K=512, MT=128, KT=16.
__global__ __launch_bounds__(256) void prep_x_tmajor(
    const float* __restrict__ x, u16* __restrict__ hi, u16* __restrict__ lo)
{
    const int e2 = blockIdx.x * 256 + threadIdx.x;
    const int kt = blockIdx.y;
    const int i = e2 & 7, l = (e2 >> 3) & 63, mt = e2 >> 9;
    const int d = mt * 16 + (l & 15);
    const int t = d >> 6, row = d & 63;
    const int k = kt * 32 + ((l >> 4) << 3) + i;
    const float v = x[((size_t)row * TT + t) * II + k];
    const u16 h = f2bf(v);
    const size_t o = (size_t)kt * 65536 + e2;
    hi[o] = h;
    lo[o] = f2bf(v - bf2f(h));
}

// ---------------------------------------------------------------------------
// Register-fragment MFMA GEMM (bf16 x3 ~= fp32), row-major output (tail proj).
// ---------------------------------------------------------------------------
__global__ __launch_bounds__(256) void gemm_mfma(
    const u16* __restrict__ Ahi, const u16* __restrict__ Alo, const int MT, const int kt0,
    const u16* __restrict__ Bhi, const u16* __restrict__ Blo, const int NT,
    const float* __restrict__ bias,
    float* __restrict__ C, const int ldc, const int KT)
{
    const int tid = threadIdx.x;
    const int w = tid >> 6, l = tid & 63;
    const int mt0 = blockIdx.y * 4;
    const int nt0 = blockIdx.x * 16 + w * 4;

    f32x4 acc[4][4];
    #pragma unroll
    for (int a = 0; a < 4; ++a)
        #pragma unroll
        for (int b = 0; b < 4; ++b) acc[a][b] = (f32x4){0.f, 0.f, 0.f, 0.f};

    bfrag ah0[4], al0[4], bh0[4], bl0[4];
    bfrag ah1[4], al1[4], bh1[4], bl1[4];

#define LOADF(AH, AL, BH, BL, KIDX) do {                                          \
    const int kk_ = (KIDX);                                                      \
    _Pragma("unroll") for (int mt = 0; mt < 4; ++mt) {                            \
        const size_t oa = (((size_t)(kt0 + kk_) * MT + mt0 + mt) * 64 + l) * 8;   \
        AH[mt] = *(const bfrag*)(Ahi + oa); AL[mt] = *(const bfrag*)(Alo + oa); } \
    _Pragma("unroll") for (int j = 0; j < 4; ++j) {                               \
        const size_t ob = (((size_t)kk_ * NT + nt0 + j) * 64 + l) * 8;            \
        BH[j] = *(const bfrag*)(Bhi + ob); BL[j] = *(const bfrag*)(Blo + ob); }   \
} while (0)

#define MFMAS(AH, AL, BH, BL) do {                                                \
    _Pragma("unroll") for (int mt = 0; mt < 4; ++mt)                              \
    _Pragma("unroll") for (int j = 0; j < 4; ++j) {                               \
        acc[mt][j] = __builtin_amdgcn_mfma_f32_16x16x32_bf16(AH[mt], BH[j], acc[mt][j], 0, 0, 0); \
        acc[mt][j] = __builtin_amdgcn_mfma_f32_16x16x32_bf16(AH[mt], BL[j], acc[mt][j], 0, 0, 0); \
        acc[mt][j] = __builtin_amdgcn_mfma_f32_16x16x32_bf16(AL[mt], BH[j], acc[mt][j], 0, 0, 0); } \
} while (0)

    LOADF(ah0, al0, bh0, bl0, 0);
    for (int kt = 0; kt < KT; kt += 2) {
        LOADF(ah1, al1, bh1, bl1, kt + 1);
        MFMAS(ah0, al0, bh0, bl0);
        if (kt + 2 < KT) LOADF(ah0, al0, bh0, bl0, kt + 2);
        MFMAS(ah1, al1, bh1, bl1);
    }

    const int rsub = (l >> 4) << 2;
    #pragma unroll
    for (int j = 0; j < 4; ++j) {
        const int col = (nt0 + j) * 16 + (l & 15);
        const float bv = bias[col];
        #pragma unroll
        for (int mt = 0; mt < 4; ++mt)
            #pragma unroll
            for (int reg = 0; reg < 4; ++reg)
                C[(size_t)((mt0 + mt) * 16 + rsub + reg) * ldc + col] = acc[mt][j][reg] + bv;
    }
#undef LOADF
#undef MFMAS
}

// ---------------------------------------------------------------------------
// xg-producer GEMM, z-fused (proven rounds 5-6).
// Output in MFMA C/D fragment layout: xgP[(((t*64 + nt)*4 + mt)*64 + l)*4 + reg]
// ---------------------------------------------------------------------------
__global__ __launch_bounds__(256) void gemm_xg(
    const u16* __restrict__ Ahi, const u16* __restrict__ Alo, const int kt0h,
    const u16* __restrict__ Bhi0, const u16* __restrict__ Blo0, const size_t bstride,
    const float* __restrict__ bias_even, const float* __restrict__ bias_odd,
    float* __restrict__ out0, const int KT)
{
    const int MT = 128, NT = 64;
    const int z = blockIdx.z;
    const int kt0 = (z >> 1) * kt0h;
    const u16* Bhi = Bhi0 + (size_t)(z & 1) * bstride;
    const u16* Blo = Blo0 + (size_t)(z & 1) * bstride;
    const float* bias = (z & 1) ? bias_odd : bias_even;
    float* out = out0 + (size_t)z * ((size_t)BB * TT * ZN);

    const int tid = threadIdx.x;
    const int w = tid >> 6, l = tid & 63;
    const int t = blockIdx.y;
    const int mt0 = t * 4;
    const int nt0 = blockIdx.x * 16 + w * 4;

    f32x4 acc[4][4];
    #pragma unroll
    for (int a = 0; a < 4; ++a)
        #pragma unroll
        for (int b = 0; b < 4; ++b) acc[a][b] = (f32x4){0.f, 0.f, 0.f, 0.f};

    bfrag ah0[4], al0[4], bh0[4], bl0[4];
    bfrag ah1[4], al1[4], bh1[4], bl1[4];

#define LOADF(AH, AL, BH, BL, KIDX) do {                                          \
    const int kk_ = (KIDX);                                                      \
    _Pragma("unroll") for (int mt = 0; mt < 4; ++mt) {                            \
        const size_t oa = (((size_t)(kt0 + kk_) * MT + mt0 + mt) * 64 + l) * 8;   \
        AH[mt] = *(const bfrag*)(Ahi + oa); AL[mt] = *(const bfrag*)(Alo + oa); } \
    _Pragma("unroll") for (int j = 0; j < 4; ++j) {                               \
        const size_t ob = (((size_t)kk_ * NT + nt0 + j) * 64 + l) * 8;            \
        BH[j] = *(const bfrag*)(Bhi + ob); BL[j] = *(const bfrag*)(Blo + ob); }   \
} while (0)

#define MFMAS(AH, AL, BH, BL) do {                                                \
    _Pragma("unroll") for (int mt = 0; mt < 4; ++mt)                              \
    _Pragma("unroll") for (int j = 0; j < 4; ++j) {                               \
        acc[mt][j] = __builtin_amdgcn_mfma_f32_16x16x32_bf16(AH[mt], BH[j], acc[mt][j], 0, 0, 0); \
        acc[mt][j] = __builtin_amdgcn_mfma_f32_16x16x32_bf16(AH[mt], BL[j], acc[mt][j], 0, 0, 0); \
        acc[mt][j] = __builtin_amdgcn_mfma_f32_16x16x32_bf16(AL[mt], BH[j], acc[mt][j], 0, 0, 0); } \
} while (0)

    LOADF(ah0, al0, bh0, bl0, 0);
    for (int kt = 0; kt < KT; kt += 2) {
        LOADF(ah1, al1, bh1, bl1, kt + 1);
        MFMAS(ah0, al0, bh0, bl0);
        if (kt + 2 < KT) LOADF(ah0, al0, bh0, bl0, kt + 2);
        MFMAS(ah1, al1, bh1, bl1);
    }
#undef LOADF
#undef MFMAS

    const int cl = l & 15;
    #pragma unroll
    for (int j = 0; j < 4; ++j) {
        const float bv = bias[(nt0 + j) * 16 + cl];
        #pragma unroll
        for (int mt = 0; mt < 4; ++mt) {
            f32x4 o = acc[mt][j];
            o[0] += bv; o[1] += bv; o[2] += bv; o[3] += bv;
            *(f32x4*)(out + ((((size_t)t * 64 + nt0 + j) * 4 + mt) * 64 + l) * 4) = o;
        }
    }
}

// ---------------------------------------------------------------------------
// Recurrence. coop: ONE cooperative launch; per-run 4-WG acquire/release
// barrier (proven round 6). h transport: u64-packed (2 x (bf16hi|bf16lo)),
// via __hip_atomic_load/store RELAXED/AGENT -- compiler-managed coherent
// dwordx2 (round-7 lesson: raw-asm loads + manual waitcnt miscompile under
// register pressure; atomics bypass the incoherent per-XCD L2 correctly).
// u64 element index: (q*8 + c)*256 + tid, c = mt*2 + regpair -> every
// instruction's 64 lanes contiguous (512B). Own quarter carried in
// double-buffered LDS; only peer quarters cross memory.
// mode-4 writes r4 DIRECTLY in proj-A fragment hi/lo layout.
// fallback (32 single-step launches): reads all 4 quarters, c/mx via global.
// run ids: 0 L1 fwd full | 1 L1 bwd full | 2..26 bwd prefix len 1..25 |
//          27..51 fwd suffix len 1..25 | 52..55 L2 (r2f,r2b,r3f,r3b)
// ---------------------------------------------------------------------------
__global__ __launch_bounds__(256, 1) void lstm_runs_k(
    const int s0, const int s1,
    const float* __restrict__ xgfP, const float* __restrict__ xgbP,
    const float* __restrict__ xg2P,
    const u16* __restrict__ Whi, const u16* __restrict__ Wlo,
    u64* __restrict__ hU, unsigned* __restrict__ bar,
    float* __restrict__ c_st, float* __restrict__ mx_st,
    float* __restrict__ out_pre, float* __restrict__ out_suf,
    u16* __restrict__ r4Ah, u16* __restrict__ r4Al)
{
    __shared__ u16 hh[2][16384];   // 64 KB: h hi, A-frag-linear, double-buffered
    __shared__ u16 hl[2][16384];   // 64 KB: h lo

    const int wg  = blockIdx.x;
    const int rid = wg >> 2;
    const int q   = wg & 3;
    const int tid = threadIdx.x;
    const int w   = tid >> 6;
    const int l   = tid & 63;
    const bool coop = (s1 - s0) > 1;

    const float* xg; int wmat, t0, dt, ns, mode, len = 0, part = 0;
    if (rid == 0)      { mode = 0; ns = 32; t0 = 0;  dt = 1;  xg = xgfP; wmat = 0; }
    else if (rid == 1) { mode = 1; ns = 32; t0 = 31; dt = -1; xg = xgbP; wmat = 1; }
    else if (rid < 27) { mode = 2; len = rid - 1;  ns = len;      t0 = len - 1; dt = -1; xg = xgbP; wmat = 1; }
    else if (rid < 52) { mode = 3; len = rid - 26; ns = 32 - len; t0 = len;     dt = 1;  xg = xgfP; wmat = 0; }
    else { mode = 4; part = rid - 52; ns = 32;
           xg = xg2P + (size_t)part * ((size_t)BB * TT * ZN);
           wmat = 2 + (part & 1); if (part & 1) { t0 = 31; dt = -1; } else { t0 = 0; dt = 1; } }

    if (!coop && s0 >= ns) return;

    // ---- weights -> registers (once per launch) ----
    bfrag WH[8][4], WL[8][4];
    {
        const u16* WHp = Whi + (size_t)wmat * 262144;
        const u16* WLp = Wlo + (size_t)wmat * 262144;
        #pragma unroll
        for (int kt = 0; kt < 8; ++kt)
            #pragma unroll
            for (int g = 0; g < 4; ++g) {
                const size_t ob = (((size_t)kt * 64 + g * 16 + q * 4 + w) * 64 + l) * 8;
                WH[kt][g] = *(const bfrag*)(WHp + ob);
                WL[kt][g] = *(const bfrag*)(WLp + ob);
            }
    }

    const int cl = l & 15, rsub = (l >> 4) << 2;
    const int hc = q * 64 + w * 16 + cl;                   // owned h column
    const int kt2 = hc >> 5, i2 = hc & 7, lhi = (hc >> 3) & 3;
    const size_t stBase = ((size_t)wg * 256 + tid) * 16;   // c/mx slot (fallback)
    // mode-4 r4 A-frag lane constants: k = part*256 + hc
    const int kk4 = part * 256 + hc;
    const int ktp = kk4 >> 5, lph = ((kk4 >> 3) & 3) * 16, ip = kk4 & 7;
    // reader decode constants (writer thread == same tid)
    const int rwq = tid >> 6, rcl = tid & 15, rsw = ((tid >> 4) & 3) << 2;

    float c[4][4], mx[4][4];
    if (s0 == 0) {
        #pragma unroll
        for (int a = 0; a < 4; ++a)
            #pragma unroll
            for (int b = 0; b < 4; ++b) { c[a][b] = 0.f; mx[a][b] = -3.4e38f; }
    } else {
        #pragma unroll
        for (int mt = 0; mt < 4; ++mt) {
            const f32x4 cv = *(const f32x4*)(c_st  + stBase + mt * 4);
            const f32x4 mv = *(const f32x4*)(mx_st + stBase + mt * 4);
            #pragma unroll
            for (int r = 0; r < 4; ++r) { c[mt][r] = cv[r]; mx[mt][r] = mv[r]; }
        }
    }

    for (int s = s0; s < s1; ++s) {
        if (s >= ns) break;
        const int t = t0 + dt * s;
        const int sp  = s & 1;
        const int spn = sp ^ 1;

        f32x4 acc[4][4];
        #pragma unroll
        for (int a = 0; a < 4; ++a)
            #pragma unroll
            for (int b = 0; b < 4; ++b) acc[a][b] = (f32x4){0.f, 0.f, 0.f, 0.f};

        if (s > 0) {
            if (coop && tid == 0) {
                while (__hip_atomic_load(&bar[rid * 32], __ATOMIC_ACQUIRE,
                                         __HIP_MEMORY_SCOPE_AGENT) < (unsigned)(4 * s)) {
                    __builtin_amdgcn_s_sleep(1);
                }
            }
            __syncthreads();   // spin-result broadcast + LDS buffer-reuse fence

            // ---- stage peer h quarters (compiler-managed coherent u64 loads) ----
            const u64* srcU = hU + ((size_t)sp * 56 + rid) * 8192;
            #pragma unroll
            for (int qp = 0; qp < 4; ++qp) {
                if (coop && qp == q) continue;             // own quarter in LDS
                const int col = qp * 64 + rwq * 16 + rcl;
                const int fbase = ((col >> 5) * 256 + ((col >> 3) & 3) * 16 + rsw) * 8
                                  + (col & 7);
                u64 vals[8];
                #pragma unroll
                for (int cc = 0; cc < 8; ++cc)
                    vals[cc] = __hip_atomic_load(srcU + (qp * 8 + cc) * 256 + tid,
                                                 __ATOMIC_RELAXED, __HIP_MEMORY_SCOPE_AGENT);
                #pragma unroll
                for (int cc = 0; cc < 8; ++cc) {
                    const int mt_ = cc >> 1, j = cc & 1;
                    const unsigned lo32 = (unsigned)vals[cc];
                    const unsigned hi32 = (unsigned)(vals[cc] >> 32);
                    const int f0 = fbase + mt_ * 512 + j * 16;
                    hh[sp][f0]     = (u16)(lo32 & 0xffffu);
                    hl[sp][f0]     = (u16)(lo32 >> 16);
                    hh[sp][f0 + 8] = (u16)(hi32 & 0xffffu);
                    hl[sp][f0 + 8] = (u16)(hi32 >> 16);
                }
            }
            __syncthreads();

            // ---- z += h @ W^T (MFMA bf16 x3) ----
            #pragma unroll
            for (int kt = 0; kt < 8; ++kt) {
                bfrag ah[4], al[4];
                #pragma unroll
                for (int mt = 0; mt < 4; ++mt) {
                    const int oa = ((kt * 4 + mt) * 64 + l) * 8;
                    ah[mt] = *(const bfrag*)&hh[sp][oa];
                    al[mt] = *(const bfrag*)&hl[sp][oa];
                }
                #pragma unroll
                for (int mt = 0; mt < 4; ++mt)
                    #pragma unroll
                    for (int g = 0; g < 4; ++g) {
                        acc[mt][g] = __builtin_amdgcn_mfma_f32_16x16x32_bf16(ah[mt], WH[kt][g], acc[mt][g], 0, 0, 0);
                        acc[mt][g] = __builtin_amdgcn_mfma_f32_16x16x32_bf16(ah[mt], WL[kt][g], acc[mt][g], 0, 0, 0);
                        acc[mt][g] = __builtin_amdgcn_mfma_f32_16x16x32_bf16(al[mt], WH[kt][g], acc[mt][g], 0, 0, 0);
                    }
            }
        }

        // ------------------ gates + state update + outputs ------------------
        u64* dstU = hU + ((size_t)spn * 56 + rid) * 8192 + q * 2048 + tid;

        #pragma unroll
        for (int mt = 0; mt < 4; ++mt) {
            f32x4 xv[4];
            #pragma unroll
            for (int g = 0; g < 4; ++g)
                xv[g] = *(const f32x4*)(xg + ((((size_t)t * 64 + g * 16 + q * 4 + w) * 4 + mt) * 64 + l) * 4);
            unsigned pk[4];
            #pragma unroll
            for (int reg = 0; reg < 4; ++reg) {
                const int row = mt * 16 + rsub + reg;
                const float zi = acc[mt][0][reg] + xv[0][reg];
                const float zf = acc[mt][1][reg] + xv[1][reg];
                const float zg = acc[mt][2][reg] + xv[2][reg];
                const float zo = acc[mt][3][reg] + xv[3][reg];
                const float c2 = sigm_(zf) * c[mt][reg] + sigm_(zi) * tanh_(zg);
                const float h2 = sigm_(zo) * tanh_(c2);
                c[mt][reg] = c2;
                const float m2 = fmaxf(mx[mt][reg], h2);
                mx[mt][reg] = m2;

                const u16 uh = f2bf(h2);
                const u16 ul = f2bf(h2 - bf2f(uh));
                pk[reg] = (unsigned)uh | ((unsigned)ul << 16);

                // own-quarter LDS carry for next step (coop; harmless otherwise)
                const int hidx = ((kt2 * 4 + mt) * 64 + lhi * 16 + rsub + reg) * 8 + i2;
                hh[spn][hidx] = uh;
                hl[spn][hidx] = ul;

                if (mode == 0) {
                    if (t <= 24)
                        out_pre[((size_t)t * BB + row) * (2 * HH) + hc] = m2;
                } else if (mode == 1) {
                    if (t >= 1 && t <= 25)
                        out_suf[((size_t)(t - 1) * BB + row) * (2 * HH) + HH + hc] = m2;
                } else if (mode == 2) {
                    if (s == ns - 1)
                        out_pre[((size_t)(len - 1) * BB + row) * (2 * HH) + HH + hc] = m2;
                } else if (mode == 3) {
                    if (s == ns - 1)
                        out_suf[((size_t)(len - 1) * BB + row) * (2 * HH) + hc] = m2;
                } else {
                    // r4 directly in proj-A fragment layout: d = row*32+t, k = kk4
                    const int d  = row * 32 + t;
                    const size_t idx = (((size_t)ktp * 128 + (d >> 4)) * 64 + lph + (d & 15)) * 8 + ip;
                    r4Ah[idx] = uh;
                    r4Al[idx] = ul;
                }
            }
            const u64 v0 = (u64)pk[0] | ((u64)pk[1] << 32);
            const u64 v1 = (u64)pk[2] | ((u64)pk[3] << 32);
            __hip_atomic_store(dstU + (mt * 2 + 0) * 256, v0,
                               __ATOMIC_RELAXED, __HIP_MEMORY_SCOPE_AGENT);
            __hip_atomic_store(dstU + (mt * 2 + 1) * 256, v1,
                               __ATOMIC_RELAXED, __HIP_MEMORY_SCOPE_AGENT);
        }

        // signal end of step s (syncthreads drains all waves' stores first)
        if (coop && s + 1 < ns) {
            __syncthreads();
            if (tid == 0)
                __hip_atomic_fetch_add(&bar[rid * 32], 1u, __ATOMIC_RELEASE,
                                       __HIP_MEMORY_SCOPE_AGENT);
        }
    }

    // persist c/mx only in fallback mode (next launch reloads)
    if (!coop && s1 < TT) {
        #pragma unroll
        for (int mt = 0; mt < 4; ++mt) {
            f32x4 cv, mv;
            #pragma unroll
            for (int r = 0; r < 4; ++r) { cv[r] = c[mt][r]; mv[r] = mx[mt][r]; }
            *(f32x4*)(c_st  + stBase + mt * 4) = cv;
            *(f32x4*)(mx_st + stBase + mt * 4) = mv;
        }
    }
}

// ---------------------------------------------------------------------------
extern "C" void kernel_launch(void* const* d_in, const int* in_sizes, int n_in,
                              void* d_out, int out_size, void* d_ws, size_t ws_size,
                              hipStream_t stream)
{
    const float* x    = (const float*)d_in[0];
    const float* wif  = (const float*)d_in[1];
    const float* whf  = (const float*)d_in[2];
    const float* bf   = (const float*)d_in[3];
    const float* wib  = (const float*)d_in[4];
    const float* whb  = (const float*)d_in[5];
    const float* bb   = (const float*)d_in[6];
    const float* w2if = (const float*)d_in[7];
    const float* w2hf = (const float*)d_in[8];
    const float* b2f  = (const float*)d_in[9];
    const float* w2ib = (const float*)d_in[10];
    const float* w2hb = (const float*)d_in[11];
    const float* b2b  = (const float*)d_in[12];
    const float* wl   = (const float*)d_in[13];
    const float* bl   = (const float*)d_in[14];

    const size_t XG = (size_t)BB * TT * ZN;          // 2,097,152 floats
    float* xgfP  = (float*)d_ws;
    float* xgbP  = xgfP + XG;
    float* xg2P  = xgbP + XG;                        // 4 consecutive arrays
    float* c_st  = xg2P + 4 * XG;                    // 224*256*16 floats
    float* mx_st = c_st + (size_t)224 * 256 * 16;

    u16* p = (u16*)(mx_st + (size_t)224 * 256 * 16);
    u16* WB8h  = p; p += (size_t)6 * 262144;   // whf,whb,w2hf,w2hb,w2if,w2ib
    u16* WB8l  = p; p += (size_t)6 * 262144;
    u16* WB16h = p; p += (size_t)2 * 524288;   // wif, wib
    u16* WB16l = p; p += (size_t)2 * 524288;
    u16* wlBh  = p; p += (size_t)524288;
    u16* wlBl  = p; p += (size_t)524288;
    u16* xAh   = p; p += (size_t)2048 * 512;
    u16* xAl   = p; p += (size_t)2048 * 512;
    u16* r4Ah  = p; p += (size_t)2048 * 1024;
    u16* r4Al  = p; p += (size_t)2048 * 1024;
    // align to 16B for u64 buffer
    u64* hU = (u64*)(((uintptr_t)p + 15) & ~(uintptr_t)15);   // 2 x 56 x 8192 u64
    unsigned* bar = (unsigned*)(hU + (size_t)2 * 56 * 8192);  // 56 x 32 (padded)

    float* outp    = (float*)d_out;
    float* out_pre = outp + (size_t)BB * TT * OO;
    float* out_suf = out_pre + (size_t)NPRE * BB * (2 * HH);

    // 0. reset per-run barrier counters (capture-safe memset node)
    hipMemsetAsync(bar, 0, (size_t)56 * 32 * sizeof(unsigned), stream);

    // 1. fragment preps (fused)
    prep_w8 <<<dim3(128, 8, 6),  256, 0, stream>>>(whf, whb, w2hf, w2hb, w2if, w2ib, WB8h, WB8l);
    prep_w16<<<dim3(128, 16, 2), 256, 0, stream>>>(wif, wib, WB16h, WB16l);
    prep_frag<<<dim3(64, 32),    256, 0, stream>>>(wl, ZN, wlBh, wlBl);      // T=32, K=1024
    prep_x_tmajor<<<dim3(256, 16), 256, 0, stream>>>(x, xAh, xAl);

    // 2. input-gate activation GEMMs -> fragment-layout xgP buffers (fused)
    gemm_xg<<<dim3(4, 32, 2), 256, 0, stream>>>(xAh, xAl, 0, WB16h, WB16l, 524288,
                                                bf, bb, xgfP, 16);
    gemm_xg<<<dim3(4, 32, 4), 256, 0, stream>>>(xAh, xAl, 8,
                                                WB8h + (size_t)4 * 262144, WB8l + (size_t)4 * 262144, 262144,
                                                b2f, b2b, xg2P, 8);

    // 3. recurrence: one cooperative launch (per-run barriers inside);
    //    fallback to 32 per-step launches if coop launch fails.
    {
        int cs0 = 0, cs1 = TT;
        const float* a_xgf = xgfP; const float* a_xgb = xgbP; const float* a_xg2 = xg2P;
        const u16* a_whi = WB8h; const u16* a_wlo = WB8l;
        u64* a_hu = hU; unsigned* a_bar = bar;
        float* a_cst = c_st; float* a_mx = mx_st;
        float* a_pre = out_pre; float* a_suf = out_suf;
        u16* a_r4h = r4Ah; u16* a_r4l = r4Al;
        void* cargs[] = { (void*)&cs0, (void*)&cs1,
                          (void*)&a_xgf, (void*)&a_xgb, (void*)&a_xg2,
                          (void*)&a_whi, (void*)&a_wlo,
                          (void*)&a_hu, (void*)&a_bar,
                          (void*)&a_cst, (void*)&a_mx,
                          (void*)&a_pre, (void*)&a_suf,
                          (void*)&a_r4h, (void*)&a_r4l };
        hipError_t ce = hipLaunchCooperativeKernel((const void*)lstm_runs_k,
                                                   dim3(224), dim3(256), cargs, 0, stream);
        if (ce != hipSuccess) {
            for (int s = 0; s < TT; ++s)
                lstm_runs_k<<<dim3(224), dim3(256), 0, stream>>>(s, s + 1,
                    xgfP, xgbP, xg2P, WB8h, WB8l, hU, bar, c_st, mx_st,
                    out_pre, out_suf, r4Ah, r4Al);
        }
    }

    // 4. final projection: output = r4 @ wl^T + bl  (r4 already in frag layout)
    gemm_mfma<<<dim3(2, 32), 256, 0, stream>>>(r4Ah, r4Al, 128, 0, wlBh, wlBl, 32, bl, outp, OO, 32);
}